// Round 5
// baseline (316.236 us; speedup 1.0000x reference)
//
#include <hip/hip_runtime.h>

// LGAN layer on a fixed 8-ring graph, N=20000, D=128, MH=256.
// R4: edge_mlp = persistent 512-thread kernel, full edge-MLP weights (128KB)
//     staged once into LDS (pre-swizzled in global: 16B-chunk c stored at
//     c ^ (row&7) within each row -> 2-way-conflict ds_read_b128).
//     Activations register-resident with sigma-permuted stage-2 weights
//     (verified in R3): slot s=32kk+8lg+j holds k=32kk+16(j>>2)+4lg+(j&3).
//     fuse_mlp/out_mlp reverted to the R1 LDS structure (measured better).

#define NN 20000
#define NE 160000
#define DD 128
#define MHD 256

typedef __attribute__((ext_vector_type(8))) short short8;
typedef __attribute__((ext_vector_type(4))) short short4v;
typedef __attribute__((ext_vector_type(4))) float f32x4;

#define SWZ(row) (((row) & 7) << 3)

__device__ __forceinline__ float bf2f(short s) {
  return __builtin_bit_cast(float, (unsigned int)((unsigned short)s) << 16);
}
__device__ __forceinline__ short f2bf(float f) {
  unsigned int u = __builtin_bit_cast(unsigned int, f);
  u = (u + 0x7FFFu + ((u >> 16) & 1u)) >> 16;
  return (short)u;
}
__device__ __forceinline__ short8 zero8() {
  short8 z;
#pragma unroll
  for (int q = 0; q < 8; ++q) z[q] = 0;
  return z;
}

#define MFMA(a, b, c) __builtin_amdgcn_mfma_f32_16x16x32_bf16((a), (b), (c), 0, 0, 0)

// ================= Kernel A: edge MLP, persistent, LDS weights =============
// wedge = We1sw (32768 shorts) ++ We2sw (32768 shorts), both chunk-swizzled.
__global__ __launch_bounds__(512, 2) void edge_mlp(
    const short* __restrict__ hbf, const short* __restrict__ wedge,
    const float* __restrict__ be1, const float* __restrict__ be2,
    short* __restrict__ he) {
  __shared__ __align__(16) short WS[65536];  // 128 KB: W1s[0:32768] W2s[32768:]
  const int t = threadIdx.x;
#pragma unroll
  for (int r = 0; r < 16; ++r) {
    const int off = r * 4096 + t * 8;
    *(short8*)&WS[off] = *(const short8*)&wedge[off];
  }
  __syncthreads();

  const int lane = t & 63, w = t >> 6;
  const int lr = lane & 15, lg = lane >> 4;
  const int sw = lr & 7;

  for (int tile = blockIdx.x; tile < NE / 256; tile += 256) {
    const int ebase = tile * 256 + w * 32;

    // X-frags: X = bf16(h[u]+h[v]); lane (lr,lg): row lr of rowset, k=32kk+8lg+j
    short8 xf[2][4];
#pragma unroll
    for (int rs = 0; rs < 2; ++rs) {
      const int e = ebase + rs * 16 + lr;
      const int j = e / NN + 1;
      const int i = e - (j - 1) * NN;
      int v = i + j;
      if (v >= NN) v -= NN;
      const short* hu = hbf + (size_t)i * DD;
      const short* hv = hbf + (size_t)v * DD;
#pragma unroll
      for (int kk = 0; kk < 4; ++kk) {
        short8 a = *(const short8*)&hu[kk * 32 + lg * 8];
        short8 b = *(const short8*)&hv[kk * 32 + lg * 8];
        short8 z;
#pragma unroll
        for (int q = 0; q < 8; ++q) z[q] = f2bf(bf2f(a[q]) + bf2f(b[q]));
        xf[rs][kk] = z;
      }
    }

    // Stage 1: 16 col-tiles of 256 mids; weights from LDS (swizzled chunks).
    short8 h1b[2][8];
#pragma unroll
    for (int ct = 0; ct < 16; ++ct) {
      short8 aw[4];
#pragma unroll
      for (int kk = 0; kk < 4; ++kk)
        aw[kk] = *(const short8*)&WS[((ct * 16 + lr) * 16 + ((kk * 4 + lg) ^ sw)) * 8];
      const f32x4 bias = *(const f32x4*)&be1[ct * 16 + 4 * lg];
#pragma unroll
      for (int rs = 0; rs < 2; ++rs) {
        f32x4 acc = bias;
#pragma unroll
        for (int kk = 0; kk < 4; ++kk) acc = MFMA(aw[kk], xf[rs][kk], acc);
#pragma unroll
        for (int q = 0; q < 4; ++q) {
          float x = acc[q] > 0.f ? acc[q] : 0.f;
          h1b[rs][ct >> 1][(ct & 1) * 4 + q] = f2bf(x);
        }
      }
    }

    // Stage 2: 8 out col-tiles; sigma-permuted weights from LDS.
#pragma unroll
    for (int ct2 = 0; ct2 < 8; ++ct2) {
      short8 aw2[8];
#pragma unroll
      for (int kk = 0; kk < 8; ++kk)
        aw2[kk] = *(const short8*)&WS[32768 +
                                      ((ct2 * 16 + lr) * 32 + ((kk * 4 + lg) ^ sw)) * 8];
      const f32x4 bias = *(const f32x4*)&be2[ct2 * 16 + 4 * lg];
#pragma unroll
      for (int rs = 0; rs < 2; ++rs) {
        f32x4 acc = bias;
#pragma unroll
        for (int kk = 0; kk < 8; ++kk) acc = MFMA(aw2[kk], h1b[rs][kk], acc);
        short4v o;
#pragma unroll
        for (int q = 0; q < 4; ++q) o[q] = f2bf(acc[q]);
        const int row = ebase + rs * 16 + lr;
        *(short4v*)&he[(size_t)row * DD + ct2 * 16 + 4 * lg] = o;
      }
    }
  }
}

// ================= Kernel B: stencil aggregation ===========================
__global__ __launch_bounds__(256) void aggregate(const short* __restrict__ he,
                                                 short* __restrict__ catb) {
  const int t = threadIdx.x;
  const int v = blockIdx.x * 16 + (t >> 4);
  const int d0 = (t & 15) * 8;
  float at[8], an[8];
#pragma unroll
  for (int q = 0; q < 8; ++q) {
    at[q] = 0.f;
    an[q] = 0.f;
  }
#pragma unroll
  for (int j = 0; j < 8; ++j) {
    const int jj = j + 1;
    const short* base = he + (size_t)j * NN * DD;
    {
      int r2 = v - jj;
      if (r2 < 0) r2 += NN;
      short8 x = *(const short8*)&base[(size_t)v * DD + d0];
      short8 y = *(const short8*)&base[(size_t)r2 * DD + d0];
#pragma unroll
      for (int q = 0; q < 8; ++q) at[q] += bf2f(x[q]) + bf2f(y[q]);
    }
#pragma unroll
    for (int o = jj - 8; o <= 8; ++o) {
      if (o == 0 || o == jj) continue;
      int r = v - o;
      if (r < 0) r += NN;
      else if (r >= NN) r -= NN;
      short8 x = *(const short8*)&base[(size_t)r * DD + d0];
#pragma unroll
      for (int q = 0; q < 8; ++q) an[q] += bf2f(x[q]);
    }
  }
  short8 o1, o2;
#pragma unroll
  for (int q = 0; q < 8; ++q) {
    o1[q] = f2bf(at[q]);
    o2[q] = f2bf(an[q]);
  }
  *(short8*)&catb[(size_t)v * 256 + d0] = o1;
  *(short8*)&catb[(size_t)v * 256 + 128 + d0] = o2;
}

// ======== R1-style helpers (LDS Xs/H1s, XOR swizzle) for fuse/out ==========
template <int NK, int LDX>
__device__ __forceinline__ void stage1s(const short* Xs, short* H1s,
                                        const short* __restrict__ W1t,
                                        const float* __restrict__ b1, int lane,
                                        int wid) {
  constexpr int K1 = NK * 32;
  const int lr = lane & 15, lg = lane >> 4;
#pragma unroll
  for (int ct = 0; ct < 4; ++ct) {
    const int wc = wid * 64 + ct * 16;
    short8 aw[NK];
#pragma unroll
    for (int kk = 0; kk < NK; ++kk)
      aw[kk] = *(const short8*)&W1t[(wc + lr) * K1 + kk * 32 + lg * 8];
    const f32x4 bias = *(const f32x4*)&b1[wc + 4 * lg];
#pragma unroll
    for (int r = 0; r < 4; ++r) {
      const int row = r * 16 + lr;
      const int swz = SWZ(row);
      short8 bx[NK];
#pragma unroll
      for (int kk = 0; kk < NK; ++kk)
        bx[kk] = *(const short8*)&Xs[row * LDX + ((kk * 32 + lg * 8) ^ swz)];
      f32x4 acc = bias;
#pragma unroll
      for (int kk = 0; kk < NK; ++kk) acc = MFMA(aw[kk], bx[kk], acc);
      short4v o;
#pragma unroll
      for (int q = 0; q < 4; ++q) {
        float v = acc[q] > 0.f ? acc[q] : 0.f;
        o[q] = f2bf(v);
      }
      *(short4v*)&H1s[row * 256 + ((wc + 4 * lg) ^ swz)] = o;
    }
  }
}

__device__ __forceinline__ void stage2s(const short* H1s,
                                        const short* __restrict__ W2t,
                                        f32x4 (&acc)[2][4], int lane, int wid) {
  const int lr = lane & 15, lg = lane >> 4;
#pragma unroll
  for (int ct = 0; ct < 2; ++ct) {
    const int wc = wid * 32 + ct * 16;
    short8 aw[8];
#pragma unroll
    for (int kk = 0; kk < 8; ++kk)
      aw[kk] = *(const short8*)&W2t[(wc + lr) * 256 + kk * 32 + lg * 8];
#pragma unroll
    for (int r = 0; r < 4; ++r) {
      const int row = r * 16 + lr;
      const int swz = SWZ(row);
#pragma unroll
      for (int kk = 0; kk < 8; ++kk) {
        short8 bh = *(const short8*)&H1s[row * 256 + ((kk * 32 + lg * 8) ^ swz)];
        acc[ct][r] = MFMA(aw[kk], bh, acc[ct][r]);
      }
    }
  }
}

// ================= Kernel C: t = MLP_f(cat) + h @ W_r + b_r ================
__global__ __launch_bounds__(256) void fuse_mlp(
    const short* __restrict__ catb, const short* __restrict__ hbf,
    const short* __restrict__ Wf1t, const float* __restrict__ bf1,
    const short* __restrict__ Wf2t, const float* __restrict__ bf2,
    const short* __restrict__ Wrt, const float* __restrict__ br,
    short* __restrict__ tout) {
  __shared__ __align__(16) short Xs[64][256];
  __shared__ __align__(16) short H1s[64][256];
  const int t = threadIdx.x;
  const int vbase = blockIdx.x * 64;
  {
    const int r = t >> 2, sub = t & 3;
    const int v = vbase + r;
    const bool valid = v < NN;
    const int swz = SWZ(r);
#pragma unroll
    for (int c = 0; c < 8; ++c) {
      const int d0 = sub * 64 + c * 8;
      short8 x = valid ? *(const short8*)&catb[(size_t)v * 256 + d0] : zero8();
      *(short8*)&Xs[r][d0 ^ swz] = x;
    }
  }
  __syncthreads();
  const int lane = t & 63, wid = t >> 6;
  stage1s<8, 256>(&Xs[0][0], &H1s[0][0], Wf1t, bf1, lane, wid);
  __syncthreads();
  const int lr = lane & 15, lg = lane >> 4;
  f32x4 acc[2][4];
#pragma unroll
  for (int ct = 0; ct < 2; ++ct) {
    const int wc = wid * 32 + ct * 16 + 4 * lg;
    f32x4 b0 = *(const f32x4*)&br[wc];
    f32x4 b1v = *(const f32x4*)&bf2[wc];
    f32x4 bias = b0 + b1v;
#pragma unroll
    for (int r = 0; r < 4; ++r) acc[ct][r] = bias;
  }
#pragma unroll
  for (int ct = 0; ct < 2; ++ct) {
    const int wc = wid * 32 + ct * 16;
    short8 aw[4];
#pragma unroll
    for (int kk = 0; kk < 4; ++kk)
      aw[kk] = *(const short8*)&Wrt[(wc + lr) * DD + kk * 32 + lg * 8];
#pragma unroll
    for (int r = 0; r < 4; ++r) {
      int v = vbase + r * 16 + lr;
      if (v >= NN) v = 0;
#pragma unroll
      for (int kk = 0; kk < 4; ++kk) {
        short8 bh = *(const short8*)&hbf[(size_t)v * DD + kk * 32 + lg * 8];
        acc[ct][r] = MFMA(aw[kk], bh, acc[ct][r]);
      }
    }
  }
  stage2s(&H1s[0][0], Wf2t, acc, lane, wid);
#pragma unroll
  for (int ct = 0; ct < 2; ++ct)
#pragma unroll
    for (int r = 0; r < 4; ++r) {
      const int v = vbase + r * 16 + lr;
      if (v < NN) {
        short4v o;
#pragma unroll
        for (int q = 0; q < 4; ++q) o[q] = f2bf(acc[ct][r][q]);
        *(short4v*)&tout[(size_t)v * DD + wid * 32 + ct * 16 + 4 * lg] = o;
      }
    }
}

// ================= Kernel D: out = MLP_p(t), fp32 out ======================
__global__ __launch_bounds__(256) void out_mlp(
    const short* __restrict__ tin, const short* __restrict__ Wp1t,
    const float* __restrict__ bp1, const short* __restrict__ Wp2t,
    const float* __restrict__ bp2, float* __restrict__ out) {
  __shared__ __align__(16) short Xs[64][128];
  __shared__ __align__(16) short H1s[64][256];
  const int t = threadIdx.x;
  const int vbase = blockIdx.x * 64;
  {
    const int r = t >> 2, sub = t & 3;
    const int v = vbase + r;
    const bool valid = v < NN;
    const int swz = SWZ(r);
#pragma unroll
    for (int c = 0; c < 4; ++c) {
      const int d0 = (sub * 4 + c) * 8;
      short8 x = valid ? *(const short8*)&tin[(size_t)v * DD + d0] : zero8();
      *(short8*)&Xs[r][d0 ^ swz] = x;
    }
  }
  __syncthreads();
  const int lane = t & 63, wid = t >> 6;
  stage1s<4, 128>(&Xs[0][0], &H1s[0][0], Wp1t, bp1, lane, wid);
  __syncthreads();
  const int lr = lane & 15, lg = lane >> 4;
  f32x4 acc[2][4];
#pragma unroll
  for (int ct = 0; ct < 2; ++ct) {
    const f32x4 bias = *(const f32x4*)&bp2[wid * 32 + ct * 16 + 4 * lg];
#pragma unroll
    for (int r = 0; r < 4; ++r) acc[ct][r] = bias;
  }
  stage2s(&H1s[0][0], Wp2t, acc, lane, wid);
#pragma unroll
  for (int ct = 0; ct < 2; ++ct)
#pragma unroll
    for (int r = 0; r < 4; ++r) {
      const int v = vbase + r * 16 + lr;
      if (v < NN)
        *(f32x4*)&out[(size_t)v * DD + wid * 32 + ct * 16 + 4 * lg] = acc[ct][r];
    }
}

// ================= conversions =============================================
__global__ __launch_bounds__(256) void cvt_h(const float* __restrict__ src,
                                             short* __restrict__ dst) {
  const size_t id = (size_t)(blockIdx.x * 256 + threadIdx.x) * 8;
  float4 a = *(const float4*)&src[id];
  float4 b = *(const float4*)&src[id + 4];
  short8 o;
  o[0] = f2bf(a.x); o[1] = f2bf(a.y); o[2] = f2bf(a.z); o[3] = f2bf(a.w);
  o[4] = f2bf(b.x); o[5] = f2bf(b.y); o[6] = f2bf(b.z); o[7] = f2bf(b.w);
  *(short8*)&dst[id] = o;
}

// sigma: stage-2 B-frag slot s -> logical mid index k (verified R3)
__device__ __forceinline__ int klog_of_slot(int s) {
  return ((s >> 5) << 5) + (((s >> 2) & 1) << 4) + (((s >> 3) & 3) << 2) + (s & 3);
}

// pool layout (shorts):
//   [0]      We1sw [256 rows][16 chunks swz]   (edge stage1, LDS image)
//   [32768]  We2sw [128 rows][32 chunks swz, sigma-permuted k]
//   [65536]  Wf1t  [256][256] k-contig
//   [131072] Wf2t  [128][256] k-contig
//   [163840] Wrt   [128][128] k-contig
//   [180224] Wp1t  [256][128] k-contig
//   [212992] Wp2t  [128][256] k-contig
__global__ __launch_bounds__(256) void cvt_weights(
    const float* __restrict__ We1, const float* __restrict__ We2,
    const float* __restrict__ Wf1, const float* __restrict__ Wf2,
    const float* __restrict__ Wr, const float* __restrict__ Wp1,
    const float* __restrict__ Wp2, short* __restrict__ dst) {
  const int id = blockIdx.x * 256 + threadIdx.x;
  float v;
  if (id < 32768) {                       // We1sw
    const int C = id >> 3, q = id & 7;
    const int m = C >> 4;
    const int c = (C & 15) ^ (m & 7);
    v = We1[(c * 8 + q) * 256 + m];
  } else if (id < 65536) {                // We2sw (swizzle + sigma)
    const int l = id - 32768;
    const int C = l >> 3, q = l & 7;
    const int m = C >> 5;
    const int c = (C & 31) ^ (m & 7);
    v = We2[klog_of_slot(c * 8 + q) * 128 + m];
  } else if (id < 131072) {               // Wf1t
    const int l = id - 65536;
    v = Wf1[(l & 255) * 256 + (l >> 8)];
  } else if (id < 163840) {               // Wf2t
    const int l = id - 131072;
    v = Wf2[(l & 255) * 128 + (l >> 8)];
  } else if (id < 180224) {               // Wrt
    const int l = id - 163840;
    v = Wr[(l & 127) * 128 + (l >> 7)];
  } else if (id < 212992) {               // Wp1t
    const int l = id - 180224;
    v = Wp1[(l & 127) * 256 + (l >> 7)];
  } else {                                // Wp2t
    const int l = id - 212992;
    v = Wp2[(l & 255) * 128 + (l >> 8)];
  }
  dst[id] = f2bf(v);
}

extern "C" void kernel_launch(void* const* d_in, const int* in_sizes, int n_in,
                              void* d_out, int out_size, void* d_ws,
                              size_t ws_size, hipStream_t stream) {
  const float* h = (const float*)d_in[0];
  const float* We1 = (const float*)d_in[4];
  const float* be1 = (const float*)d_in[5];
  const float* We2 = (const float*)d_in[6];
  const float* be2 = (const float*)d_in[7];
  const float* Wf1 = (const float*)d_in[8];
  const float* bf1 = (const float*)d_in[9];
  const float* Wf2 = (const float*)d_in[10];
  const float* bf2 = (const float*)d_in[11];
  const float* Wr = (const float*)d_in[12];
  const float* br = (const float*)d_in[13];
  const float* Wp1 = (const float*)d_in[14];
  const float* bp1 = (const float*)d_in[15];
  const float* Wp2 = (const float*)d_in[16];
  const float* bp2 = (const float*)d_in[17];

  char* ws = (char*)d_ws;
  short* hbf = (short*)ws;                      // 20000*128*2   = 5,120,000
  short* he = (short*)(ws + 5120000);           // 160000*128*2  = 40,960,000
  short* catb = (short*)(ws + 46080000);        // 20000*256*2   = 10,240,000
  short* tbuf = (short*)(ws + 56320000);        // 20000*128*2   = 5,120,000
  short* wpool = (short*)(ws + 61440000);       // 245760*2      = 491,520
  short* wedge = wpool;                         // We1sw ++ We2sw (65536)
  short* Wf1t = wpool + 65536;
  short* Wf2t = Wf1t + 65536;
  short* Wrt = Wf2t + 32768;
  short* Wp1t = Wrt + 16384;
  short* Wp2t = Wp1t + 32768;

  cvt_h<<<1250, 256, 0, stream>>>(h, hbf);
  cvt_weights<<<960, 256, 0, stream>>>(We1, We2, Wf1, Wf2, Wr, Wp1, Wp2, wpool);
  edge_mlp<<<256, 512, 0, stream>>>(hbf, wedge, be1, be2, he);
  aggregate<<<NN / 16, 256, 0, stream>>>(he, catb);
  fuse_mlp<<<(NN + 63) / 64, 256, 0, stream>>>(catb, hbf, Wf1t, bf1, Wf2t, bf2,
                                               Wrt, br, tbuf);
  out_mlp<<<(NN + 63) / 64, 256, 0, stream>>>(tbuf, Wp1t, bp1, Wp2t, bp2,
                                              (float*)d_out);
}

// Round 7
// 121.874 us; speedup vs baseline: 2.5948x; 2.5948x over previous
//
#include <hip/hip_runtime.h>

// LGAN layer on a fixed 8-ring graph, N=20000, D=128, MH=256.
// R6: edge_mlp = 4-phase quarter-staged weights (32 KB LDS/block, >=3 blk/CU),
//     register-resident X/H1 via verified sigma-permuted stage-2 layout.
//     Per phase: stage 32KB (W1 quarter + W2 quarter, chunk-swizzled) ->
//     barrier -> stage1 MFMA (h1 regs) + stage2 partial accumulate -> barrier.
//     fuse_mlp/out_mlp/aggregate: R1 measured-known forms, unchanged.
// R7: resubmit (container infra failure last round).

#define NN 20000
#define NE 160000
#define DD 128
#define MHD 256

typedef __attribute__((ext_vector_type(8))) short short8;
typedef __attribute__((ext_vector_type(4))) short short4v;
typedef __attribute__((ext_vector_type(4))) float f32x4;

#define SWZ(row) (((row) & 7) << 3)

__device__ __forceinline__ float bf2f(short s) {
  return __builtin_bit_cast(float, (unsigned int)((unsigned short)s) << 16);
}
__device__ __forceinline__ short f2bf(float f) {
  unsigned int u = __builtin_bit_cast(unsigned int, f);
  u = (u + 0x7FFFu + ((u >> 16) & 1u)) >> 16;
  return (short)u;
}
__device__ __forceinline__ short8 zero8() {
  short8 z;
#pragma unroll
  for (int q = 0; q < 8; ++q) z[q] = 0;
  return z;
}

#define MFMA(a, b, c) __builtin_amdgcn_mfma_f32_16x16x32_bf16((a), (b), (c), 0, 0, 0)

// ============ Kernel A: edge MLP, 4-phase quarter-staged weights ============
// wq image (65536 shorts): per phase p (16384): WA_p[64 lm][128 e] then
// WB_p[128 o][64 e]; within each row, 16B chunk ch holds logical chunk
// ch^(row&mask) (mask 15 for WA, 7 for WB); WB logical slot s holds
// W2[p*64 + sigma6(s)][o].
__global__ __launch_bounds__(256, 3) void edge_mlp(
    const short* __restrict__ hbf, const short* __restrict__ wq,
    const float* __restrict__ be1, const float* __restrict__ be2,
    short* __restrict__ he) {
  __shared__ __align__(16) short WS[16384];  // 32 KB: WA[0:8192] WB[8192:16384]
  const int t = threadIdx.x;
  const int lane = t & 63, w = t >> 6;
  const int lr = lane & 15, lg = lane >> 4;
  const int ebase = blockIdx.x * 128 + w * 32;

  // X-frags: X = bf16(h[u]+h[v]); lane (lr,lg): row lr of rowset, k=32kk+8lg+j
  short8 xf[2][4];
#pragma unroll
  for (int rs = 0; rs < 2; ++rs) {
    const int e = ebase + rs * 16 + lr;
    const int j = e / NN + 1;
    const int i = e - (j - 1) * NN;
    int v = i + j;
    if (v >= NN) v -= NN;
    const short* hu = hbf + (size_t)i * DD;
    const short* hv = hbf + (size_t)v * DD;
#pragma unroll
    for (int kk = 0; kk < 4; ++kk) {
      short8 a = *(const short8*)&hu[kk * 32 + lg * 8];
      short8 b = *(const short8*)&hv[kk * 32 + lg * 8];
      short8 z;
#pragma unroll
      for (int q = 0; q < 8; ++q) z[q] = f2bf(bf2f(a[q]) + bf2f(b[q]));
      xf[rs][kk] = z;
    }
  }

  // acc init with stage-2 bias
  f32x4 acc[2][8];
#pragma unroll
  for (int ct2 = 0; ct2 < 8; ++ct2) {
    const f32x4 b2 = *(const f32x4*)&be2[ct2 * 16 + 4 * lg];
    acc[0][ct2] = b2;
    acc[1][ct2] = b2;
  }

#pragma unroll 1
  for (int p = 0; p < 4; ++p) {
    // stage this phase's 32 KB (chunk-interleaved: lane-consecutive chunks)
    {
      short8 stg[8];
#pragma unroll
      for (int c = 0; c < 8; ++c)
        stg[c] = *(const short8*)&wq[p * 16384 + (c * 256 + t) * 8];
#pragma unroll
      for (int c = 0; c < 8; ++c) *(short8*)&WS[(c * 256 + t) * 8] = stg[c];
    }
    __syncthreads();

    // stage1: 64 mids of this quarter -> h1 regs (sigma-packed)
    short8 h1q[2][2];
#pragma unroll
    for (int ct = 0; ct < 4; ++ct) {
      short8 aw[4];
#pragma unroll
      for (int kk = 0; kk < 4; ++kk)
        aw[kk] = *(const short8*)&WS[(ct * 16 + lr) * 128 +
                                     (((kk * 4 + lg) ^ lr) << 3)];
      const f32x4 b1 = *(const f32x4*)&be1[p * 64 + ct * 16 + 4 * lg];
#pragma unroll
      for (int rs = 0; rs < 2; ++rs) {
        f32x4 a1 = b1;
#pragma unroll
        for (int kk = 0; kk < 4; ++kk) a1 = MFMA(aw[kk], xf[rs][kk], a1);
#pragma unroll
        for (int q = 0; q < 4; ++q) {
          float x = a1[q] > 0.f ? a1[q] : 0.f;
          h1q[rs][ct >> 1][(ct & 1) * 4 + q] = f2bf(x);
        }
      }
    }

    // stage2 partial: acc += W2-quarter @ h1-quarter
#pragma unroll
    for (int kk2 = 0; kk2 < 2; ++kk2)
#pragma unroll
      for (int ct2 = 0; ct2 < 8; ++ct2) {
        short8 aw2 = *(const short8*)&WS[8192 + (ct2 * 16 + lr) * 64 +
                                         (((kk2 * 4 + lg) ^ (lr & 7)) << 3)];
        acc[0][ct2] = MFMA(aw2, h1q[0][kk2], acc[0][ct2]);
        acc[1][ct2] = MFMA(aw2, h1q[1][kk2], acc[1][ct2]);
      }
    __syncthreads();  // done reading; next phase may overwrite WS
  }

  // store
#pragma unroll
  for (int rs = 0; rs < 2; ++rs)
#pragma unroll
    for (int ct2 = 0; ct2 < 8; ++ct2) {
      short4v o;
#pragma unroll
      for (int q = 0; q < 4; ++q) o[q] = f2bf(acc[rs][ct2][q]);
      *(short4v*)&he[(size_t)(ebase + rs * 16 + lr) * DD + ct2 * 16 + 4 * lg] = o;
    }
}

// ================= Kernel B: stencil aggregation ===========================
__global__ __launch_bounds__(256) void aggregate(const short* __restrict__ he,
                                                 short* __restrict__ catb) {
  const int t = threadIdx.x;
  const int v = blockIdx.x * 16 + (t >> 4);
  const int d0 = (t & 15) * 8;
  float at[8], an[8];
#pragma unroll
  for (int q = 0; q < 8; ++q) {
    at[q] = 0.f;
    an[q] = 0.f;
  }
#pragma unroll
  for (int j = 0; j < 8; ++j) {
    const int jj = j + 1;
    const short* base = he + (size_t)j * NN * DD;
    {
      int r2 = v - jj;
      if (r2 < 0) r2 += NN;
      short8 x = *(const short8*)&base[(size_t)v * DD + d0];
      short8 y = *(const short8*)&base[(size_t)r2 * DD + d0];
#pragma unroll
      for (int q = 0; q < 8; ++q) at[q] += bf2f(x[q]) + bf2f(y[q]);
    }
#pragma unroll
    for (int o = jj - 8; o <= 8; ++o) {
      if (o == 0 || o == jj) continue;
      int r = v - o;
      if (r < 0) r += NN;
      else if (r >= NN) r -= NN;
      short8 x = *(const short8*)&base[(size_t)r * DD + d0];
#pragma unroll
      for (int q = 0; q < 8; ++q) an[q] += bf2f(x[q]);
    }
  }
  short8 o1, o2;
#pragma unroll
  for (int q = 0; q < 8; ++q) {
    o1[q] = f2bf(at[q]);
    o2[q] = f2bf(an[q]);
  }
  *(short8*)&catb[(size_t)v * 256 + d0] = o1;
  *(short8*)&catb[(size_t)v * 256 + 128 + d0] = o2;
}

// ======== R1-style helpers (LDS Xs/H1s, XOR swizzle) for fuse/out ==========
template <int NK, int LDX>
__device__ __forceinline__ void stage1s(const short* Xs, short* H1s,
                                        const short* __restrict__ W1t,
                                        const float* __restrict__ b1, int lane,
                                        int wid) {
  constexpr int K1 = NK * 32;
  const int lr = lane & 15, lg = lane >> 4;
#pragma unroll
  for (int ct = 0; ct < 4; ++ct) {
    const int wc = wid * 64 + ct * 16;
    short8 aw[NK];
#pragma unroll
    for (int kk = 0; kk < NK; ++kk)
      aw[kk] = *(const short8*)&W1t[(wc + lr) * K1 + kk * 32 + lg * 8];
    const f32x4 bias = *(const f32x4*)&b1[wc + 4 * lg];
#pragma unroll
    for (int r = 0; r < 4; ++r) {
      const int row = r * 16 + lr;
      const int swz = SWZ(row);
      short8 bx[NK];
#pragma unroll
      for (int kk = 0; kk < NK; ++kk)
        bx[kk] = *(const short8*)&Xs[row * LDX + ((kk * 32 + lg * 8) ^ swz)];
      f32x4 acc = bias;
#pragma unroll
      for (int kk = 0; kk < NK; ++kk) acc = MFMA(aw[kk], bx[kk], acc);
      short4v o;
#pragma unroll
      for (int q = 0; q < 4; ++q) {
        float v = acc[q] > 0.f ? acc[q] : 0.f;
        o[q] = f2bf(v);
      }
      *(short4v*)&H1s[row * 256 + ((wc + 4 * lg) ^ swz)] = o;
    }
  }
}

__device__ __forceinline__ void stage2s(const short* H1s,
                                        const short* __restrict__ W2t,
                                        f32x4 (&acc)[2][4], int lane, int wid) {
  const int lr = lane & 15, lg = lane >> 4;
#pragma unroll
  for (int ct = 0; ct < 2; ++ct) {
    const int wc = wid * 32 + ct * 16;
    short8 aw[8];
#pragma unroll
    for (int kk = 0; kk < 8; ++kk)
      aw[kk] = *(const short8*)&W2t[(wc + lr) * 256 + kk * 32 + lg * 8];
#pragma unroll
    for (int r = 0; r < 4; ++r) {
      const int row = r * 16 + lr;
      const int swz = SWZ(row);
#pragma unroll
      for (int kk = 0; kk < 8; ++kk) {
        short8 bh = *(const short8*)&H1s[row * 256 + ((kk * 32 + lg * 8) ^ swz)];
        acc[ct][r] = MFMA(aw[kk], bh, acc[ct][r]);
      }
    }
  }
}

// ================= Kernel C: t = MLP_f(cat) + h @ W_r + b_r ================
__global__ __launch_bounds__(256) void fuse_mlp(
    const short* __restrict__ catb, const short* __restrict__ hbf,
    const short* __restrict__ Wf1t, const float* __restrict__ bf1,
    const short* __restrict__ Wf2t, const float* __restrict__ bf2,
    const short* __restrict__ Wrt, const float* __restrict__ br,
    short* __restrict__ tout) {
  __shared__ __align__(16) short Xs[64][256];
  __shared__ __align__(16) short H1s[64][256];
  const int t = threadIdx.x;
  const int vbase = blockIdx.x * 64;
  {
    const int r = t >> 2, sub = t & 3;
    const int v = vbase + r;
    const bool valid = v < NN;
    const int swz = SWZ(r);
#pragma unroll
    for (int c = 0; c < 8; ++c) {
      const int d0 = sub * 64 + c * 8;
      short8 x = valid ? *(const short8*)&catb[(size_t)v * 256 + d0] : zero8();
      *(short8*)&Xs[r][d0 ^ swz] = x;
    }
  }
  __syncthreads();
  const int lane = t & 63, wid = t >> 6;
  stage1s<8, 256>(&Xs[0][0], &H1s[0][0], Wf1t, bf1, lane, wid);
  __syncthreads();
  const int lr = lane & 15, lg = lane >> 4;
  f32x4 acc[2][4];
#pragma unroll
  for (int ct = 0; ct < 2; ++ct) {
    const int wc = wid * 32 + ct * 16 + 4 * lg;
    f32x4 b0 = *(const f32x4*)&br[wc];
    f32x4 b1v = *(const f32x4*)&bf2[wc];
    f32x4 bias = b0 + b1v;
#pragma unroll
    for (int r = 0; r < 4; ++r) acc[ct][r] = bias;
  }
#pragma unroll
  for (int ct = 0; ct < 2; ++ct) {
    const int wc = wid * 32 + ct * 16;
    short8 aw[4];
#pragma unroll
    for (int kk = 0; kk < 4; ++kk)
      aw[kk] = *(const short8*)&Wrt[(wc + lr) * DD + kk * 32 + lg * 8];
#pragma unroll
    for (int r = 0; r < 4; ++r) {
      int v = vbase + r * 16 + lr;
      if (v >= NN) v = 0;
#pragma unroll
      for (int kk = 0; kk < 4; ++kk) {
        short8 bh = *(const short8*)&hbf[(size_t)v * DD + kk * 32 + lg * 8];
        acc[ct][r] = MFMA(aw[kk], bh, acc[ct][r]);
      }
    }
  }
  stage2s(&H1s[0][0], Wf2t, acc, lane, wid);
#pragma unroll
  for (int ct = 0; ct < 2; ++ct)
#pragma unroll
    for (int r = 0; r < 4; ++r) {
      const int v = vbase + r * 16 + lr;
      if (v < NN) {
        short4v o;
#pragma unroll
        for (int q = 0; q < 4; ++q) o[q] = f2bf(acc[ct][r][q]);
        *(short4v*)&tout[(size_t)v * DD + wid * 32 + ct * 16 + 4 * lg] = o;
      }
    }
}

// ================= Kernel D: out = MLP_p(t), fp32 out ======================
__global__ __launch_bounds__(256) void out_mlp(
    const short* __restrict__ tin, const short* __restrict__ Wp1t,
    const float* __restrict__ bp1, const short* __restrict__ Wp2t,
    const float* __restrict__ bp2, float* __restrict__ out) {
  __shared__ __align__(16) short Xs[64][128];
  __shared__ __align__(16) short H1s[64][256];
  const int t = threadIdx.x;
  const int vbase = blockIdx.x * 64;
  {
    const int r = t >> 2, sub = t & 3;
    const int v = vbase + r;
    const bool valid = v < NN;
    const int swz = SWZ(r);
#pragma unroll
    for (int c = 0; c < 4; ++c) {
      const int d0 = (sub * 4 + c) * 8;
      short8 x = valid ? *(const short8*)&tin[(size_t)v * DD + d0] : zero8();
      *(short8*)&Xs[r][d0 ^ swz] = x;
    }
  }
  __syncthreads();
  const int lane = t & 63, wid = t >> 6;
  stage1s<4, 128>(&Xs[0][0], &H1s[0][0], Wp1t, bp1, lane, wid);
  __syncthreads();
  const int lr = lane & 15, lg = lane >> 4;
  f32x4 acc[2][4];
#pragma unroll
  for (int ct = 0; ct < 2; ++ct) {
    const f32x4 bias = *(const f32x4*)&bp2[wid * 32 + ct * 16 + 4 * lg];
#pragma unroll
    for (int r = 0; r < 4; ++r) acc[ct][r] = bias;
  }
  stage2s(&H1s[0][0], Wp2t, acc, lane, wid);
#pragma unroll
  for (int ct = 0; ct < 2; ++ct)
#pragma unroll
    for (int r = 0; r < 4; ++r) {
      const int v = vbase + r * 16 + lr;
      if (v < NN)
        *(f32x4*)&out[(size_t)v * DD + wid * 32 + ct * 16 + 4 * lg] = acc[ct][r];
    }
}

// ================= conversions =============================================
__global__ __launch_bounds__(256) void cvt_h(const float* __restrict__ src,
                                             short* __restrict__ dst) {
  const size_t id = (size_t)(blockIdx.x * 256 + threadIdx.x) * 8;
  float4 a = *(const float4*)&src[id];
  float4 b = *(const float4*)&src[id + 4];
  short8 o;
  o[0] = f2bf(a.x); o[1] = f2bf(a.y); o[2] = f2bf(a.z); o[3] = f2bf(a.w);
  o[4] = f2bf(b.x); o[5] = f2bf(b.y); o[6] = f2bf(b.z); o[7] = f2bf(b.w);
  *(short8*)&dst[id] = o;
}

// sigma: stage-2 B-frag slot s -> logical mid index (bit permutation;
// valid for 6/7/8-bit s). Verified R3.
__device__ __forceinline__ int klog_of_slot(int s) {
  return ((s >> 5) << 5) + (((s >> 2) & 1) << 4) + (((s >> 3) & 3) << 2) + (s & 3);
}

// pool layout (shorts):
//   [0]      wq: edge quarter images, 4 x (WA_p 8192 + WB_p 8192) = 65536
//   [65536]  Wf1t  [256][256] k-contig
//   [131072] Wf2t  [128][256] k-contig
//   [163840] Wrt   [128][128] k-contig
//   [180224] Wp1t  [256][128] k-contig
//   [212992] Wp2t  [128][256] k-contig
__global__ __launch_bounds__(256) void cvt_weights(
    const float* __restrict__ We1, const float* __restrict__ We2,
    const float* __restrict__ Wf1, const float* __restrict__ Wf2,
    const float* __restrict__ Wr, const float* __restrict__ Wp1,
    const float* __restrict__ Wp2, short* __restrict__ dst) {
  const int id = blockIdx.x * 256 + threadIdx.x;
  float v;
  if (id < 65536) {                       // edge quarter images
    const int p = id >> 14, r = id & 16383;
    if (r < 8192) {                       // WA_p: [64 lm][128 e], chunk-swz
      const int lm = r >> 7, e = r & 127;
      const int k = (((e >> 3) ^ (lm & 15)) << 3) | (e & 7);
      v = We1[k * 256 + p * 64 + lm];
    } else {                              // WB_p: [128 o][64 e], swz + sigma
      const int i2 = r - 8192;
      const int o = i2 >> 6, e = i2 & 63;
      const int s = (((e >> 3) ^ (o & 7)) << 3) | (e & 7);
      v = We2[(p * 64 + klog_of_slot(s)) * 128 + o];
    }
  } else if (id < 131072) {               // Wf1t
    const int l = id - 65536;
    v = Wf1[(l & 255) * 256 + (l >> 8)];
  } else if (id < 163840) {               // Wf2t
    const int l = id - 131072;
    v = Wf2[(l & 255) * 128 + (l >> 8)];
  } else if (id < 180224) {               // Wrt
    const int l = id - 163840;
    v = Wr[(l & 127) * 128 + (l >> 7)];
  } else if (id < 212992) {               // Wp1t
    const int l = id - 180224;
    v = Wp1[(l & 127) * 256 + (l >> 7)];
  } else {                                // Wp2t
    const int l = id - 212992;
    v = Wp2[(l & 255) * 128 + (l >> 8)];
  }
  dst[id] = f2bf(v);
}

extern "C" void kernel_launch(void* const* d_in, const int* in_sizes, int n_in,
                              void* d_out, int out_size, void* d_ws,
                              size_t ws_size, hipStream_t stream) {
  const float* h = (const float*)d_in[0];
  const float* We1 = (const float*)d_in[4];
  const float* be1 = (const float*)d_in[5];
  const float* We2 = (const float*)d_in[6];
  const float* be2 = (const float*)d_in[7];
  const float* Wf1 = (const float*)d_in[8];
  const float* bf1 = (const float*)d_in[9];
  const float* Wf2 = (const float*)d_in[10];
  const float* bf2 = (const float*)d_in[11];
  const float* Wr = (const float*)d_in[12];
  const float* br = (const float*)d_in[13];
  const float* Wp1 = (const float*)d_in[14];
  const float* bp1 = (const float*)d_in[15];
  const float* Wp2 = (const float*)d_in[16];
  const float* bp2 = (const float*)d_in[17];

  char* ws = (char*)d_ws;
  short* hbf = (short*)ws;                      // 20000*128*2   = 5,120,000
  short* he = (short*)(ws + 5120000);           // 160000*128*2  = 40,960,000
  short* catb = (short*)(ws + 46080000);        // 20000*256*2   = 10,240,000
  short* tbuf = (short*)(ws + 56320000);        // 20000*128*2   = 5,120,000
  short* wpool = (short*)(ws + 61440000);       // 245760*2      = 491,520
  short* wq = wpool;                            // edge quarter images (65536)
  short* Wf1t = wpool + 65536;
  short* Wf2t = Wf1t + 65536;
  short* Wrt = Wf2t + 32768;
  short* Wp1t = Wrt + 16384;
  short* Wp2t = Wp1t + 32768;

  cvt_h<<<1250, 256, 0, stream>>>(h, hbf);
  cvt_weights<<<960, 256, 0, stream>>>(We1, We2, Wf1, Wf2, Wr, Wp1, Wp2, wpool);
  edge_mlp<<<NE / 128, 256, 0, stream>>>(hbf, wq, be1, be2, he);
  aggregate<<<NN / 16, 256, 0, stream>>>(he, catb);
  fuse_mlp<<<(NN + 63) / 64, 256, 0, stream>>>(catb, hbf, Wf1t, bf1, Wf2t, bf2,
                                               Wrt, br, tbuf);
  out_mlp<<<(NN + 63) / 64, 256, 0, stream>>>(tbuf, Wp1t, bp1, Wp2t, bp2,
                                              (float*)d_out);
}